// Round 9
// baseline (33.573 us; speedup 1.0000x reference)
//
#include <hip/hip_runtime.h>

#define DIM 120
#define NB 16            // batch rows per block
#define NBP 20           // padded LDS stride in dwords (b128-aligned)
#define BLOCK 256        // one thread per output row within a tile
#define NG (NB / 4)      // float4 groups along b
#define GX 16            // persistent x-groups (16*128 blocks = 8/CU exactly)

// ---- Fused preprocess: CSR row pointers + packed {i1,i2,palette} entries ----
__global__ void pre_kernel(const int* __restrict__ out_idx, int K, int H,
                           int* __restrict__ row_start,
                           const int* __restrict__ i1, const int* __restrict__ i2,
                           const int* __restrict__ cb, const float* __restrict__ pal,
                           uint2* __restrict__ ent) {
    int t = blockIdx.x * blockDim.x + threadIdx.x;
    if (t <= H) {
        int lo = 0, hi = K;
        while (lo < hi) {
            int mid = (lo + hi) >> 1;
            if (out_idx[mid] < t) lo = mid + 1; else hi = mid;
        }
        row_start[t] = lo;
    }
    if (t < K) {
        uint2 e;
        e.x = (unsigned)i1[t] | ((unsigned)i2[t] << 16);
        e.y = __float_as_uint(pal[cb[t]]);
        ent[t] = e;
    }
}

// ---- Main: block stages its NB-batch tile ONCE, then sweeps a contiguous
//      chunk of o-tiles. Hot loop identical to R8. ----
__global__ __launch_bounds__(BLOCK, 8) void tp_kernel(
    const float* __restrict__ in1, const float* __restrict__ in2,
    const uint2* __restrict__ ent, const int* __restrict__ row_start,
    float* __restrict__ out, int H, int ntiles) {
    __shared__ __align__(16) float s1t[DIM * NBP];
    __shared__ __align__(16) float s2t[DIM * NBP];

    // --- stage NB batch-rows transposed to [d][b] (once per block) ---
    const int b0 = blockIdx.y * NB;
    for (int t = threadIdx.x; t < 2 * DIM * NG; t += BLOCK) {
        const int arr = (t >= DIM * NG);
        const int c = arr ? t - DIM * NG : t;
        const int d = c % DIM;
        const int g = c / DIM;
        const float* __restrict__ src = arr ? in2 : in1;
        const size_t base = (size_t)(b0 + 4 * g) * DIM + d;
        float4 v;
        v.x = src[base + 0 * DIM];
        v.y = src[base + 1 * DIM];
        v.z = src[base + 2 * DIM];
        v.w = src[base + 3 * DIM];
        float* dst = arr ? s2t : s1t;
        *(float4*)(dst + d * NBP + 4 * g) = v;
    }
    __syncthreads();

    // --- contiguous tile chunk for this x-group ---
    const int gx = blockIdx.x;              // 0..GX-1 (fastest dim -> id%8 = XCD stripe)
    const int q = ntiles / GX, r = ntiles % GX;
    const int t0 = gx * q + (gx < r ? gx : r);
    const int t1 = t0 + q + (gx < r ? 1 : 0);

    for (int tile = t0; tile < t1; ++tile) {
        const int o = tile * BLOCK + (int)threadIdx.x;
        if (o >= H) continue;
        const int k0 = row_start[o];
        const int k1 = row_start[o + 1];

        float acc[NB];
#pragma unroll
        for (int b = 0; b < NB; ++b) acc[b] = 0.0f;

        for (int k = k0; k < k1; ++k) {
            const uint2 e = ent[k];
            const float4* __restrict__ pa = (const float4*)(s1t + (e.x & 0xffffu) * NBP);
            const float4* __restrict__ pc = (const float4*)(s2t + (e.x >> 16) * NBP);
            const float v = __uint_as_float(e.y);
#pragma unroll
            for (int j = 0; j < NG; ++j) {
                const float4 x4 = pa[j];
                const float4 y4 = pc[j];
                acc[4 * j + 0] = fmaf(v * x4.x, y4.x, acc[4 * j + 0]);
                acc[4 * j + 1] = fmaf(v * x4.y, y4.y, acc[4 * j + 1]);
                acc[4 * j + 2] = fmaf(v * x4.z, y4.z, acc[4 * j + 2]);
                acc[4 * j + 3] = fmaf(v * x4.w, y4.w, acc[4 * j + 3]);
            }
        }

#pragma unroll
        for (int b = 0; b < NB; ++b)
            out[(size_t)(b0 + b) * H + o] = acc[b];
    }
}

extern "C" void kernel_launch(void* const* d_in, const int* in_sizes, int n_in,
                              void* d_out, int out_size, void* d_ws, size_t ws_size,
                              hipStream_t stream) {
    const float* in1 = (const float*)d_in[0];
    const float* in2 = (const float*)d_in[1];
    const float* pal = (const float*)d_in[2];
    const int*   i1  = (const int*)d_in[3];
    const int*   i2  = (const int*)d_in[4];
    const int*   oi  = (const int*)d_in[5];
    const int*   cb  = (const int*)d_in[6];

    const int K = in_sizes[3];
    const int B = in_sizes[0] / DIM;   // 2048
    const int H = out_size / B;        // 14400

    uint2* ent = (uint2*)d_ws;
    int* row_start = (int*)((char*)d_ws + (size_t)K * sizeof(uint2));

    {
        const int n = (K > H + 1) ? K : (H + 1);
        pre_kernel<<<(n + 255) / 256, 256, 0, stream>>>(oi, K, H, row_start,
                                                        i1, i2, cb, pal, ent);
    }

    const int ntiles = (H + BLOCK - 1) / BLOCK;   // 57
    dim3 grid(GX, B / NB);                        // 16 x 128 = 2048 blocks
    tp_kernel<<<grid, BLOCK, 0, stream>>>(in1, in2, ent, row_start,
                                          (float*)d_out, H, ntiles);
}